// Round 6
// baseline (613.481 us; speedup 1.0000x reference)
//
#include <hip/hip_runtime.h>
#include <math.h>

#define BATCH 8192
#define TPB   32      // half-waves: 256 blocks -> 1 wave on each of 256 CUs
#define SEG   50      // 98 segments * 50 = 4900 steps (4900..4999 unobserved)

// R5 post-mortem: VGPR=132 (pipeline finally register-resident) yet time
// unchanged at ~197 cyc/step = serial-ish memory service. The invariant
// across R1-R5: every load of a wave shares its low 15 address bits
// (32KB-stride column walk) -> burst collapses onto one L2 channel/set.
// R6: pass 1 permutes dW into [sg][bx][r][i] so each segment is a
// contiguous 6400B block; pass 2 = R5 pipeline with saddr+imm addressing.

#define REP50(M) M(0) M(1) M(2) M(3) M(4) M(5) M(6) M(7) M(8) M(9) \
  M(10) M(11) M(12) M(13) M(14) M(15) M(16) M(17) M(18) M(19) \
  M(20) M(21) M(22) M(23) M(24) M(25) M(26) M(27) M(28) M(29) \
  M(30) M(31) M(32) M(33) M(34) M(35) M(36) M(37) M(38) M(39) \
  M(40) M(41) M(42) M(43) M(44) M(45) M(46) M(47) M(48) M(49)

#define DECL_A(k) float A##k = 0.0f;
#define DECL_B(k) float B##k = 0.0f;

// ---- contiguous-segment loads: uniform saddr + imm offsets, voffset=lane*4 ----
#define LD25OFF \
  "global_load_dword %[d0], %[vo], %[sb]\n\t" \
  "global_load_dword %[d1], %[vo], %[sb] offset:128\n\t" \
  "global_load_dword %[d2], %[vo], %[sb] offset:256\n\t" \
  "global_load_dword %[d3], %[vo], %[sb] offset:384\n\t" \
  "global_load_dword %[d4], %[vo], %[sb] offset:512\n\t" \
  "global_load_dword %[d5], %[vo], %[sb] offset:640\n\t" \
  "global_load_dword %[d6], %[vo], %[sb] offset:768\n\t" \
  "global_load_dword %[d7], %[vo], %[sb] offset:896\n\t" \
  "global_load_dword %[d8], %[vo], %[sb] offset:1024\n\t" \
  "global_load_dword %[d9], %[vo], %[sb] offset:1152\n\t" \
  "global_load_dword %[d10], %[vo], %[sb] offset:1280\n\t" \
  "global_load_dword %[d11], %[vo], %[sb] offset:1408\n\t" \
  "global_load_dword %[d12], %[vo], %[sb] offset:1536\n\t" \
  "global_load_dword %[d13], %[vo], %[sb] offset:1664\n\t" \
  "global_load_dword %[d14], %[vo], %[sb] offset:1792\n\t" \
  "global_load_dword %[d15], %[vo], %[sb] offset:1920\n\t" \
  "global_load_dword %[d16], %[vo], %[sb] offset:2048\n\t" \
  "global_load_dword %[d17], %[vo], %[sb] offset:2176\n\t" \
  "global_load_dword %[d18], %[vo], %[sb] offset:2304\n\t" \
  "global_load_dword %[d19], %[vo], %[sb] offset:2432\n\t" \
  "global_load_dword %[d20], %[vo], %[sb] offset:2560\n\t" \
  "global_load_dword %[d21], %[vo], %[sb] offset:2688\n\t" \
  "global_load_dword %[d22], %[vo], %[sb] offset:2816\n\t" \
  "global_load_dword %[d23], %[vo], %[sb] offset:2944\n\t" \
  "global_load_dword %[d24], %[vo], %[sb] offset:3072"

#define LOAD_LO(P, ptr) asm volatile(LD25OFF \
  : [d0]"=v"(P##0),[d1]"=v"(P##1),[d2]"=v"(P##2),[d3]"=v"(P##3), \
    [d4]"=v"(P##4),[d5]"=v"(P##5),[d6]"=v"(P##6),[d7]"=v"(P##7), \
    [d8]"=v"(P##8),[d9]"=v"(P##9),[d10]"=v"(P##10),[d11]"=v"(P##11), \
    [d12]"=v"(P##12),[d13]"=v"(P##13),[d14]"=v"(P##14),[d15]"=v"(P##15), \
    [d16]"=v"(P##16),[d17]"=v"(P##17),[d18]"=v"(P##18),[d19]"=v"(P##19), \
    [d20]"=v"(P##20),[d21]"=v"(P##21),[d22]"=v"(P##22),[d23]"=v"(P##23), \
    [d24]"=v"(P##24) \
  : [vo]"v"(vlane), [sb]"s"(ptr))

#define LOAD_HI(P, ptr) asm volatile(LD25OFF \
  : [d0]"=v"(P##25),[d1]"=v"(P##26),[d2]"=v"(P##27),[d3]"=v"(P##28), \
    [d4]"=v"(P##29),[d5]"=v"(P##30),[d6]"=v"(P##31),[d7]"=v"(P##32), \
    [d8]"=v"(P##33),[d9]"=v"(P##34),[d10]"=v"(P##35),[d11]"=v"(P##36), \
    [d12]"=v"(P##37),[d13]"=v"(P##38),[d14]"=v"(P##39),[d15]"=v"(P##40), \
    [d16]"=v"(P##41),[d17]"=v"(P##42),[d18]"=v"(P##43),[d19]"=v"(P##44), \
    [d20]"=v"(P##45),[d21]"=v"(P##46),[d22]"=v"(P##47),[d23]"=v"(P##48), \
    [d24]"=v"(P##49) \
  : [vo]"v"(vlane), [sb]"s"(ptr))

// ---- fallback (R5) loads: rolling voffset, 32KB stride ----
#define LDL(k) "global_load_dword %[d" #k "], %[ob], %[sb]\n\t" \
               "v_add_u32 %[ob], 0x8000, %[ob]\n\t"
#define LD25B LDL(0) LDL(1) LDL(2) LDL(3) LDL(4) LDL(5) LDL(6) LDL(7) \
  LDL(8) LDL(9) LDL(10) LDL(11) LDL(12) LDL(13) LDL(14) LDL(15) LDL(16) \
  LDL(17) LDL(18) LDL(19) LDL(20) LDL(21) LDL(22) LDL(23) LDL(24)

#define LOADD_LO(P) asm volatile(LD25B \
  : [d0]"=v"(P##0),[d1]"=v"(P##1),[d2]"=v"(P##2),[d3]"=v"(P##3), \
    [d4]"=v"(P##4),[d5]"=v"(P##5),[d6]"=v"(P##6),[d7]"=v"(P##7), \
    [d8]"=v"(P##8),[d9]"=v"(P##9),[d10]"=v"(P##10),[d11]"=v"(P##11), \
    [d12]"=v"(P##12),[d13]"=v"(P##13),[d14]"=v"(P##14),[d15]"=v"(P##15), \
    [d16]"=v"(P##16),[d17]"=v"(P##17),[d18]"=v"(P##18),[d19]"=v"(P##19), \
    [d20]"=v"(P##20),[d21]"=v"(P##21),[d22]"=v"(P##22),[d23]"=v"(P##23), \
    [d24]"=v"(P##24),[ob]"+v"(ob) \
  : [sb]"s"(dWp))
#define LOADD_HI(P) asm volatile(LD25B \
  : [d0]"=v"(P##25),[d1]"=v"(P##26),[d2]"=v"(P##27),[d3]"=v"(P##28), \
    [d4]"=v"(P##29),[d5]"=v"(P##30),[d6]"=v"(P##31),[d7]"=v"(P##32), \
    [d8]"=v"(P##33),[d9]"=v"(P##34),[d10]"=v"(P##35),[d11]"=v"(P##36), \
    [d12]"=v"(P##37),[d13]"=v"(P##38),[d14]"=v"(P##39),[d15]"=v"(P##40), \
    [d16]"=v"(P##41),[d17]"=v"(P##42),[d18]"=v"(P##43),[d19]"=v"(P##44), \
    [d20]"=v"(P##45),[d21]"=v"(P##46),[d22]"=v"(P##47),[d23]"=v"(P##48), \
    [d24]"=v"(P##49),[ob]"+v"(ob) \
  : [sb]"s"(dWp))

// wait until only the newest 50 (the just-issued other buffer) remain
#define WAIT_LO(P) asm volatile("s_waitcnt vmcnt(50)" \
  : "+v"(P##0),"+v"(P##1),"+v"(P##2),"+v"(P##3),"+v"(P##4), \
    "+v"(P##5),"+v"(P##6),"+v"(P##7),"+v"(P##8),"+v"(P##9), \
    "+v"(P##10),"+v"(P##11),"+v"(P##12),"+v"(P##13),"+v"(P##14), \
    "+v"(P##15),"+v"(P##16),"+v"(P##17),"+v"(P##18),"+v"(P##19), \
    "+v"(P##20),"+v"(P##21),"+v"(P##22),"+v"(P##23),"+v"(P##24))
#define WAIT_HI(P) asm volatile("s_waitcnt vmcnt(50)" \
  : "+v"(P##25),"+v"(P##26),"+v"(P##27),"+v"(P##28),"+v"(P##29), \
    "+v"(P##30),"+v"(P##31),"+v"(P##32),"+v"(P##33),"+v"(P##34), \
    "+v"(P##35),"+v"(P##36),"+v"(P##37),"+v"(P##38),"+v"(P##39), \
    "+v"(P##40),"+v"(P##41),"+v"(P##42),"+v"(P##43),"+v"(P##44), \
    "+v"(P##45),"+v"(P##46),"+v"(P##47),"+v"(P##48),"+v"(P##49))

#define STEP_BODY(dwv) { \
    float dw  = (dwv); \
    float pr  = dtrec * r0; \
    float ps  = pr * s; \
    float r0a = r0 * c1 + c2; \
    float sq  = sqrtf(fabsf(r0)); \
    float g   = dw * volc; \
    s  = s - ps; \
    i_ = i_ * ci + ps; \
    r0 = r0a + sq * g; }

#define STEP_A(k) STEP_BODY(A##k)
#define STEP_B(k) STEP_BODY(B##k)

#define SIM_PROLOG \
    const int bx = blockIdx.x; \
    const int lane = threadIdx.x; \
    const int b = bx * TPB + lane; \
    const float u_in     = uu[b]; \
    const float inf_rate = cond[b * 4 + 0]; \
    const float rec      = cond[b * 4 + 1]; \
    const float mr       = cond[b * 4 + 2]; \
    const float vol      = cond[b * 4 + 3]; \
    const float dt    = 0.01f; \
    const float r0i   = inf_rate / rec; \
    const float dtrec = dt * rec; \
    const float ci    = 1.0f - dtrec; \
    const float c1    = 1.0f - dt * mr; \
    const float c2    = (dt * mr) * r0i; \
    const float volc  = vol * sqrtf(dt); \
    float s  = 0.99f; \
    float i_ = 0.01f; \
    float r0 = r0i; \
    float maxv = -1.0f, maxat = 0.0f; \
    float prevlx = 0.0f, sum = 0.0f, sumsq = 0.0f; \
    int   reccount = 0; \
    REP50(DECL_A) \
    REP50(DECL_B)

#define RECORD_BLOCK { \
    float x = __builtin_isfinite(i_) ? i_ : 0.0f; \
    x = fmaxf(x, 1e-5f); \
    float lx = logf(x); \
    if (reccount > 0) { float d = lx - prevlx; sum += d; sumsq += d * d; } \
    prevlx = lx; \
    if (x > maxv) { maxv = x; maxat = (float)reccount; } \
    ++reccount; }

#define SIM_EPILOG \
    asm volatile("s_waitcnt vmcnt(0)" \
      : "+v"(A0),"+v"(A1),"+v"(A2),"+v"(A3),"+v"(A4),"+v"(A5),"+v"(A6), \
        "+v"(A7),"+v"(A8),"+v"(A9),"+v"(A10),"+v"(A11),"+v"(A12),"+v"(A13), \
        "+v"(A14),"+v"(A15),"+v"(A16),"+v"(A17),"+v"(A18),"+v"(A19), \
        "+v"(A20),"+v"(A21),"+v"(A22),"+v"(A23),"+v"(A24) : : "memory"); \
    asm volatile("s_waitcnt vmcnt(0)" \
      : "+v"(A25),"+v"(A26),"+v"(A27),"+v"(A28),"+v"(A29),"+v"(A30), \
        "+v"(A31),"+v"(A32),"+v"(A33),"+v"(A34),"+v"(A35),"+v"(A36), \
        "+v"(A37),"+v"(A38),"+v"(A39),"+v"(A40),"+v"(A41),"+v"(A42), \
        "+v"(A43),"+v"(A44),"+v"(A45),"+v"(A46),"+v"(A47),"+v"(A48), \
        "+v"(A49) : : "memory"); \
    float mean = sum / 48.0f; \
    float var  = sumsq / 48.0f - mean * mean; \
    var = fmaxf(var, 0.0f); \
    out[b * 3 + 0] = maxv; \
    out[b * 3 + 1] = (maxat + u_in) / 49.0f; \
    out[b * 3 + 2] = sqrtf(var);

// ---- pass 1: dW[row][b] -> dWr[sg][bx][r][i], rows 0..4899 only ----
__global__ __launch_bounds__(256)
void reshuffle_kernel(const float* __restrict__ src, float* __restrict__ dst)
{
    const unsigned t  = blockIdx.x * 256u + threadIdx.x;  // float4 id
    const unsigned e4 = t * 4u;
    const unsigned row = e4 >> 13;          // /8192
    const unsigned b0  = e4 & 8191u;
    const unsigned sg  = row / 50u;
    const unsigned r   = row - sg * 50u;
    const unsigned bx  = b0 >> 5;
    const unsigned i0  = b0 & 31u;          // multiple of 4
    const float4 v = ((const float4*)src)[t];
    const unsigned dst4 = ((sg * 256u + bx) * 50u + r) * 8u + (i0 >> 2);
    ((float4*)dst)[dst4] = v;
}

// ---- pass 2: sim on reshuffled layout ----
__global__ __attribute__((amdgpu_flat_work_group_size(TPB, TPB),
                          amdgpu_waves_per_eu(1, 1)))
void sir_sde_reshuf(const float* __restrict__ cond,
                    const float* __restrict__ dWr,
                    const float* __restrict__ uu,
                    float* __restrict__ out)
{
    SIM_PROLOG
    const unsigned vlane = (unsigned)lane * 4u;   // per-lane byte offset

    const float* pA0 = dWr + (size_t)bx * 1600;   // segment 0 region
    LOAD_LO(A, pA0); LOAD_HI(A, pA0 + 800);

#pragma clang loop unroll(disable)
    for (int sg = 0; sg < 98; sg += 2) {
        const float* pB = dWr + ((size_t)(sg + 1) * 256 + bx) * 1600;
        LOAD_LO(B, pB); LOAD_HI(B, pB + 800);

        WAIT_LO(A); WAIT_HI(A);
        REP50(STEP_A)

        const int nxt = (sg + 2 < 98) ? (sg + 2) : 0;   // dummy reload on last iter
        const float* pA = dWr + ((size_t)nxt * 256 + bx) * 1600;
        LOAD_LO(A, pA); LOAD_HI(A, pA + 800);

        WAIT_LO(B); WAIT_HI(B);
        REP50(STEP_B)

        RECORD_BLOCK          // t = 50*sg+99 == 99 (mod 100) every iteration
    }

    SIM_EPILOG
}

// ---- fallback: R5 direct-strided kernel (used only if ws too small) ----
__global__ __attribute__((amdgpu_flat_work_group_size(TPB, TPB),
                          amdgpu_waves_per_eu(1, 1)))
void sir_sde_direct(const float* __restrict__ cond,
                    const float* __restrict__ dW,
                    const float* __restrict__ uu,
                    float* __restrict__ out)
{
    SIM_PROLOG
    const float* dWp = dW;
    unsigned ob = (unsigned)b * 4u;

    LOADD_LO(A); LOADD_HI(A);

#pragma clang loop unroll(disable)
    for (int sg = 0; sg < 98; sg += 2) {
        LOADD_LO(B); LOADD_HI(B);
        WAIT_LO(A); WAIT_HI(A);
        REP50(STEP_A)
        LOADD_LO(A); LOADD_HI(A);
        WAIT_LO(B); WAIT_HI(B);
        REP50(STEP_B)
        RECORD_BLOCK
    }

    SIM_EPILOG
}

extern "C" void kernel_launch(void* const* d_in, const int* in_sizes, int n_in,
                              void* d_out, int out_size, void* d_ws, size_t ws_size,
                              hipStream_t stream)
{
    (void)in_sizes; (void)n_in; (void)out_size;
    const float* cond = (const float*)d_in[0];
    const float* dW   = (const float*)d_in[1];
    const float* uu   = (const float*)d_in[2];
    float* out = (float*)d_out;

    const size_t need = (size_t)4900 * 8192 * 4;   // 160.6 MB
    if (ws_size >= need) {
        float* dWr = (float*)d_ws;
        hipLaunchKernelGGL(reshuffle_kernel, dim3(4900u * 8192u / 4u / 256u),
                           dim3(256), 0, stream, dW, dWr);
        hipLaunchKernelGGL(sir_sde_reshuf, dim3(BATCH / TPB), dim3(TPB), 0,
                           stream, cond, dWr, uu, out);
    } else {
        hipLaunchKernelGGL(sir_sde_direct, dim3(BATCH / TPB), dim3(TPB), 0,
                           stream, cond, dW, uu, out);
    }
}

// Round 8
// 600.609 us; speedup vs baseline: 1.0214x; 1.0214x over previous
//
#include <hip/hip_runtime.h>
#include <math.h>

#define BATCH 8192
#define TPB_FB 32

// R7 post-mortem: 128-bit "+v" tie chains on async load destinations can get
// a v_mov copy inserted BEFORE the s_waitcnt (tie-coalescing failure under
// pressure) -> reads of not-yet-landed registers -> launch-trash dw -> 1e35.
// R8: no registers in the async path at all. global_load_lds DMA (no dest
// VGPRs) into a quad-buffered LDS ring; 3 loader waves rotate segments
// (attacks the measured ~3-line-per-wave memory concurrency limit); sim wave
// 0 computes from landed buffers with plain-C LDS reads (compiler-managed
// lgkmcnt). Raw asm s_barrier so the compiler can't attach a vmcnt(0) drain.

typedef float f4v __attribute__((ext_vector_type(4)));
typedef __attribute__((address_space(1))) const void gas_v;
typedef __attribute__((address_space(3))) void las_v;

#define STEP_BODY(dwv) { \
    float dw  = (dwv); \
    float pr  = dtrec * r0; \
    float ps  = pr * s; \
    float r0a = r0 * c1 + c2; \
    float sq  = sqrtf(fabsf(r0)); \
    float g   = dw * volc; \
    s  = s - ps; \
    i_ = i_ * ci + ps; \
    r0 = r0a + sq * g; }

#define RECORD_BLOCK { \
    float x = __builtin_isfinite(i_) ? i_ : 0.0f; \
    x = fmaxf(x, 1e-5f); \
    float lx = logf(x); \
    if (reccount > 0) { float d = lx - prevlx; sum += d; sumsq += d * d; } \
    prevlx = lx; \
    if (x > maxv) { maxv = x; maxat = (float)reccount; } \
    ++reccount; }

#define SIM_CONSTS \
    const float dt    = 0.01f; \
    const float r0i   = inf_rate / rec; \
    const float dtrec = dt * rec; \
    const float ci    = 1.0f - dtrec; \
    const float c1    = 1.0f - dt * mr; \
    const float c2    = (dt * mr) * r0i; \
    const float volc  = vol * sqrtf(dt); \
    float s  = 0.99f; \
    float i_ = 0.01f; \
    float r0 = r0i; \
    float maxv = -1.0f, maxat = 0.0f; \
    float prevlx = 0.0f, sum = 0.0f, sumsq = 0.0f; \
    int   reccount = 0;

// ---- pass 1: dW[row][b] -> dWr[seg][bx][rg][i][c] (seg=100 rows, rg=row/4,
// i=lane, c=row%4). Region per (seg,bx) = 3200 floats, fully contiguous. ----
__global__ __launch_bounds__(256)
void reshuffle_x4(const float* __restrict__ src, float* __restrict__ dst)
{
    const unsigned t  = blockIdx.x * 256u + threadIdx.x;   // dst float4 slot id
    const unsigned i  = t & 31u;
    const unsigned r1 = t >> 5;
    const unsigned rg = r1 % 25u;
    const unsigned r2 = r1 / 25u;
    const unsigned bx = r2 & 255u;
    const unsigned sl = r2 >> 8;            // 0..48
    const unsigned seg = 48u - sl;          // write reversed: seg 0 L3-MRU
    const unsigned row0 = seg * 100u + rg * 4u;
    const unsigned bcol = bx * 32u + i;
    f4v v;
    v.x = src[(size_t)(row0 + 0) * BATCH + bcol];
    v.y = src[(size_t)(row0 + 1) * BATCH + bcol];
    v.z = src[(size_t)(row0 + 2) * BATCH + bcol];
    v.w = src[(size_t)(row0 + 3) * BATCH + bcol];
    const size_t dst4 = ((size_t)(seg * 256u + bx) * 25u + rg) * 32u + i;
    ((f4v*)dst)[dst4] = v;
}

// DMA one 12800B segment region into LDS: 12 full-wave chunks (64 lanes x
// 16B = 1024B) + one half-wave 512B tail. LDS base is wave-uniform; HW
// writes lane l at base + l*16 (matches the [rg][i][c] layout exactly).
__device__ __forceinline__ void dma_seg(const float* reg, float* lb, int l64)
{
#pragma unroll
    for (int j = 0; j < 12; ++j)
        __builtin_amdgcn_global_load_lds((gas_v*)(reg + j * 256 + l64 * 4),
                                         (las_v*)(lb + j * 256), 16, 0, 0);
    if (l64 < 32)
        __builtin_amdgcn_global_load_lds((gas_v*)(reg + 3072 + l64 * 4),
                                         (las_v*)(lb + 3072), 16, 0, 0);
}

// ---- pass 2: 4 waves/block. wave 0 lanes 0-31 simulate; waves 1-3 load. ----
__global__ __attribute__((amdgpu_flat_work_group_size(256, 256),
                          amdgpu_waves_per_eu(1, 1)))
void sir_sde_lds(const float* __restrict__ cond,
                 const float* __restrict__ dWr,
                 const float* __restrict__ uu,
                 float* __restrict__ out)
{
    __shared__ __align__(16) float sbuf[4][3200];   // 51.2 KB quad-ring

    const int bx   = blockIdx.x;
    const int lane = threadIdx.x & 31;
    const int l64  = threadIdx.x & 63;
    const int wv   = threadIdx.x >> 6;              // 0..3
    const int b    = bx * 32 + lane;                // valid for all threads

    const float u_in     = uu[b];
    const float inf_rate = cond[b * 4 + 0];
    const float rec      = cond[b * 4 + 1];
    const float mr       = cond[b * 4 + 2];
    const float vol      = cond[b * 4 + 3];
    SIM_CONSTS

    const size_t regstride = 3200;                  // floats per (seg,bx) region

    // prologue: segs 0,1 loaded and drained before anyone reads
    if (wv == 1) dma_seg(dWr + ((size_t)0 * 256 + bx) * regstride, sbuf[0], l64);
    if (wv == 2) dma_seg(dWr + ((size_t)1 * 256 + bx) * regstride, sbuf[1], l64);
    if (wv == 1 || wv == 2)
        asm volatile("s_waitcnt vmcnt(0)" ::: "memory");
    __syncthreads();

#pragma clang loop unroll(disable)
    for (int k = 0; k < 49; ++k) {
        // owner of seg k+1 drains ITS dma (issued a full segment ago)
        if (k + 1 <= 48 && wv == 1 + (k + 1) % 3)
            asm volatile("s_waitcnt vmcnt(0)" ::: "memory");
        // raw barrier: no compiler-attached vmcnt(0) drain of fresh DMAs
        asm volatile("s_barrier" ::: "memory");

        // owner of seg k+2 issues its DMA (lands during this+next compute)
        if (k + 2 <= 48 && wv == 1 + (k + 2) % 3)
            dma_seg(dWr + ((size_t)(k + 2) * 256 + bx) * regstride,
                    sbuf[(k + 2) & 3], l64);

        // sim wave: 100 steps from the landed buffer
        if (threadIdx.x < 32) {
            const float* sb = sbuf[k & 3];
#pragma unroll
            for (int j = 0; j < 25; ++j) {
                const f4v d = *(const f4v*)(sb + j * 128 + lane * 4);
                STEP_BODY(d.x) STEP_BODY(d.y) STEP_BODY(d.z) STEP_BODY(d.w)
            }
            RECORD_BLOCK          // t = 100*k + 99
        }
    }

    if (threadIdx.x < 32) {
        float mean = sum / 48.0f;
        float var  = sumsq / 48.0f - mean * mean;
        var = fmaxf(var, 0.0f);
        out[b * 3 + 0] = maxv;
        out[b * 3 + 1] = (maxat + u_in) / 49.0f;
        out[b * 3 + 2] = sqrtf(var);
    }
}

// ---- fallback: R5-proven direct-strided register pipeline (ws too small) ----
#define REP50(M) M(0) M(1) M(2) M(3) M(4) M(5) M(6) M(7) M(8) M(9) \
  M(10) M(11) M(12) M(13) M(14) M(15) M(16) M(17) M(18) M(19) \
  M(20) M(21) M(22) M(23) M(24) M(25) M(26) M(27) M(28) M(29) \
  M(30) M(31) M(32) M(33) M(34) M(35) M(36) M(37) M(38) M(39) \
  M(40) M(41) M(42) M(43) M(44) M(45) M(46) M(47) M(48) M(49)
#define DECL_a(k) float a##k = 0.0f;
#define DECL_b(k) float b##k = 0.0f;
#define LDL(k) "global_load_dword %[d" #k "], %[ob], %[sb]\n\t" \
               "v_add_u32 %[ob], 0x8000, %[ob]\n\t"
#define LD25B LDL(0) LDL(1) LDL(2) LDL(3) LDL(4) LDL(5) LDL(6) LDL(7) \
  LDL(8) LDL(9) LDL(10) LDL(11) LDL(12) LDL(13) LDL(14) LDL(15) LDL(16) \
  LDL(17) LDL(18) LDL(19) LDL(20) LDL(21) LDL(22) LDL(23) LDL(24)
#define LOADD_LO(P) asm volatile(LD25B \
  : [d0]"=v"(P##0),[d1]"=v"(P##1),[d2]"=v"(P##2),[d3]"=v"(P##3), \
    [d4]"=v"(P##4),[d5]"=v"(P##5),[d6]"=v"(P##6),[d7]"=v"(P##7), \
    [d8]"=v"(P##8),[d9]"=v"(P##9),[d10]"=v"(P##10),[d11]"=v"(P##11), \
    [d12]"=v"(P##12),[d13]"=v"(P##13),[d14]"=v"(P##14),[d15]"=v"(P##15), \
    [d16]"=v"(P##16),[d17]"=v"(P##17),[d18]"=v"(P##18),[d19]"=v"(P##19), \
    [d20]"=v"(P##20),[d21]"=v"(P##21),[d22]"=v"(P##22),[d23]"=v"(P##23), \
    [d24]"=v"(P##24),[ob]"+v"(ob) \
  : [sb]"s"(dWp))
#define LOADD_HI(P) asm volatile(LD25B \
  : [d0]"=v"(P##25),[d1]"=v"(P##26),[d2]"=v"(P##27),[d3]"=v"(P##28), \
    [d4]"=v"(P##29),[d5]"=v"(P##30),[d6]"=v"(P##31),[d7]"=v"(P##32), \
    [d8]"=v"(P##33),[d9]"=v"(P##34),[d10]"=v"(P##35),[d11]"=v"(P##36), \
    [d12]"=v"(P##37),[d13]"=v"(P##38),[d14]"=v"(P##39),[d15]"=v"(P##40), \
    [d16]"=v"(P##41),[d17]"=v"(P##42),[d18]"=v"(P##43),[d19]"=v"(P##44), \
    [d20]"=v"(P##45),[d21]"=v"(P##46),[d22]"=v"(P##47),[d23]"=v"(P##48), \
    [d24]"=v"(P##49),[ob]"+v"(ob) \
  : [sb]"s"(dWp))
#define WAIT_LO(P) asm volatile("s_waitcnt vmcnt(50)" \
  : "+v"(P##0),"+v"(P##1),"+v"(P##2),"+v"(P##3),"+v"(P##4), \
    "+v"(P##5),"+v"(P##6),"+v"(P##7),"+v"(P##8),"+v"(P##9), \
    "+v"(P##10),"+v"(P##11),"+v"(P##12),"+v"(P##13),"+v"(P##14), \
    "+v"(P##15),"+v"(P##16),"+v"(P##17),"+v"(P##18),"+v"(P##19), \
    "+v"(P##20),"+v"(P##21),"+v"(P##22),"+v"(P##23),"+v"(P##24))
#define WAIT_HI(P) asm volatile("s_waitcnt vmcnt(50)" \
  : "+v"(P##25),"+v"(P##26),"+v"(P##27),"+v"(P##28),"+v"(P##29), \
    "+v"(P##30),"+v"(P##31),"+v"(P##32),"+v"(P##33),"+v"(P##34), \
    "+v"(P##35),"+v"(P##36),"+v"(P##37),"+v"(P##38),"+v"(P##39), \
    "+v"(P##40),"+v"(P##41),"+v"(P##42),"+v"(P##43),"+v"(P##44), \
    "+v"(P##45),"+v"(P##46),"+v"(P##47),"+v"(P##48),"+v"(P##49))
#define STEP_a(k) STEP_BODY(a##k)
#define STEP_b(k) STEP_BODY(b##k)

__global__ __attribute__((amdgpu_flat_work_group_size(TPB_FB, TPB_FB),
                          amdgpu_waves_per_eu(1, 1)))
void sir_sde_direct(const float* __restrict__ cond,
                    const float* __restrict__ dW,
                    const float* __restrict__ uu,
                    float* __restrict__ out)
{
    const int bx   = blockIdx.x;
    const int lane = threadIdx.x;
    const int b    = bx * TPB_FB + lane;
    const float u_in     = uu[b];
    const float inf_rate = cond[b * 4 + 0];
    const float rec      = cond[b * 4 + 1];
    const float mr       = cond[b * 4 + 2];
    const float vol      = cond[b * 4 + 3];
    SIM_CONSTS
    REP50(DECL_a)
    REP50(DECL_b)
    const float* dWp = dW;
    unsigned ob = (unsigned)b * 4u;

    LOADD_LO(a); LOADD_HI(a);
#pragma clang loop unroll(disable)
    for (int sg = 0; sg < 98; sg += 2) {
        LOADD_LO(b); LOADD_HI(b);
        WAIT_LO(a); WAIT_HI(a);
        REP50(STEP_a)
        LOADD_LO(a); LOADD_HI(a);
        WAIT_LO(b); WAIT_HI(b);
        REP50(STEP_b)
        RECORD_BLOCK
    }
    asm volatile("s_waitcnt vmcnt(0)" ::: "memory");
    float mean = sum / 48.0f;
    float var  = sumsq / 48.0f - mean * mean;
    var = fmaxf(var, 0.0f);
    out[b * 3 + 0] = maxv;
    out[b * 3 + 1] = (maxat + u_in) / 49.0f;
    out[b * 3 + 2] = sqrtf(var);
}

extern "C" void kernel_launch(void* const* d_in, const int* in_sizes, int n_in,
                              void* d_out, int out_size, void* d_ws, size_t ws_size,
                              hipStream_t stream)
{
    (void)in_sizes; (void)n_in; (void)out_size;
    const float* cond = (const float*)d_in[0];
    const float* dW   = (const float*)d_in[1];
    const float* uu   = (const float*)d_in[2];
    float* out = (float*)d_out;

    const size_t need = (size_t)4900 * BATCH * 4;   // 160.6 MB
    if (ws_size >= need) {
        float* dWr = (float*)d_ws;
        hipLaunchKernelGGL(reshuffle_x4, dim3(39200), dim3(256), 0, stream,
                           dW, dWr);
        hipLaunchKernelGGL(sir_sde_lds, dim3(256), dim3(256), 0, stream,
                           cond, dWr, uu, out);
    } else {
        hipLaunchKernelGGL(sir_sde_direct, dim3(BATCH / TPB_FB), dim3(TPB_FB),
                           0, stream, cond, dW, uu, out);
    }
}